// Round 1
// baseline (25.341 us; speedup 1.0000x reference)
//
#include <hip/hip_runtime.h>

#define EPSV 1e-6f

// x,y: [16, 3, 512, 512] f32. Per pixel (b,h,w): 3-vector across channel axis.
// angle = acos( dot(x+eps, y+eps) / (|x+eps||y+eps| + eps) ); out = mean(angle_deg)/100.

__global__ __launch_bounds__(256) void color_loss_partial(
    const float* __restrict__ x, const float* __restrict__ y,
    float* __restrict__ partial)
{
    constexpr int S = 512 * 512;             // channel plane elements
    constexpr long long NG = (16LL * S) / 4; // float4 pixel-groups = 1048576
    float acc = 0.f;

    const long long stride = (long long)gridDim.x * blockDim.x;
    for (long long g = (long long)blockIdx.x * blockDim.x + threadIdx.x; g < NG; g += stride) {
        long long p  = g << 2;          // first pixel of this group
        long long b  = p >> 18;         // p / S  (S = 2^18)
        long long hw = p & (S - 1);     // p % S  (groups never cross a plane: S % 4 == 0)
        const float* xb = x + b * (3LL * S) + hw;
        const float* yb = y + b * (3LL * S) + hw;

        float4 X0 = *(const float4*)(xb);
        float4 X1 = *(const float4*)(xb + S);
        float4 X2 = *(const float4*)(xb + 2 * S);
        float4 Y0 = *(const float4*)(yb);
        float4 Y1 = *(const float4*)(yb + S);
        float4 Y2 = *(const float4*)(yb + 2 * S);

        float xs0[4] = {X0.x, X0.y, X0.z, X0.w};
        float xs1[4] = {X1.x, X1.y, X1.z, X1.w};
        float xs2[4] = {X2.x, X2.y, X2.z, X2.w};
        float ys0[4] = {Y0.x, Y0.y, Y0.z, Y0.w};
        float ys1[4] = {Y1.x, Y1.y, Y1.z, Y1.w};
        float ys2[4] = {Y2.x, Y2.y, Y2.z, Y2.w};

#pragma unroll
        for (int j = 0; j < 4; ++j) {
            float a  = xs0[j] + EPSV, bb = xs1[j] + EPSV, c = xs2[j] + EPSV;
            float d  = ys0[j] + EPSV, e  = ys1[j] + EPSV, f = ys2[j] + EPSV;
            float lx = sqrtf(a * a + bb * bb + c * c);
            float ly = sqrtf(d * d + e * e + f * f);
            float dt = a * d + bb * e + c * f;
            float ca = dt / (lx * ly + EPSV);   // NOTE: no clamp — matches reference
            acc += acosf(ca);
        }
    }

    // wave (64-lane) reduction, then cross-wave via LDS
    for (int off = 32; off; off >>= 1) acc += __shfl_down(acc, off, 64);
    __shared__ float sacc[4];
    const int wave = threadIdx.x >> 6;
    const int lane = threadIdx.x & 63;
    if (lane == 0) sacc[wave] = acc;
    __syncthreads();
    if (threadIdx.x == 0)
        partial[blockIdx.x] = sacc[0] + sacc[1] + sacc[2] + sacc[3];
}

__global__ __launch_bounds__(256) void color_loss_final(
    const float* __restrict__ partial, int n, float* __restrict__ out)
{
    float s = 0.f;
    for (int i = threadIdx.x; i < n; i += 256) s += partial[i];
    for (int off = 32; off; off >>= 1) s += __shfl_down(s, off, 64);
    __shared__ float sacc[4];
    const int wave = threadIdx.x >> 6;
    const int lane = threadIdx.x & 63;
    if (lane == 0) sacc[wave] = s;
    __syncthreads();
    if (threadIdx.x == 0) {
        float total = sacc[0] + sacc[1] + sacc[2] + sacc[3];
        // angle_deg = angle * 180/pi ; mean over 16*512*512 pixels ; /100
        const float scale = (float)(180.0 / (3.141592653589793 * 4194304.0 * 100.0));
        out[0] = total * scale;
    }
}

extern "C" void kernel_launch(void* const* d_in, const int* in_sizes, int n_in,
                              void* d_out, int out_size, void* d_ws, size_t ws_size,
                              hipStream_t stream)
{
    const float* x = (const float*)d_in[0];
    const float* y = (const float*)d_in[1];
    float* out     = (float*)d_out;
    float* partial = (float*)d_ws;

    const int NBLK = 2048;
    color_loss_partial<<<NBLK, 256, 0, stream>>>(x, y, partial);
    color_loss_final<<<1, 256, 0, stream>>>(partial, NBLK, out);
}